// Round 3
// baseline (794.596 us; speedup 1.0000x reference)
//
#include <hip/hip_runtime.h>

#define PS    7
#define PADV  3
#define PP    49      // PS*PS
#define FDIM  147     // 3*PP
#define KNN   5

// Fixed problem instance: t=8, p=65536, H=W=256
#define T_IMG 8
#define HPIX  256
#define WPIX  256
#define NPIX  (T_IMG * HPIX * WPIX)   // 524288 pixels

#define TS    16                       // tile size (own pixels)
#define TPD   (HPIX / TS)              // 16 tiles per dim
#define NTILE (T_IMG * TPD * TPD)      // 2048 tiles
#define CAP   512                      // entry slots per tile (mean ~274, sigma ~17)
#define EXT   (TS + PS - 1)            // 22 = own + halo
#define PLANE 528                      // LDS plane stride in floats (breaks 32-bank alignment)

// workspace layout (bytes)
#define WS_CNT  0                              // u32[NTILE]
#define WS_ENT  (64 * 1024)                    // uint2[NTILE*CAP] = 8 MB
#define WS_VID  (WS_ENT + NTILE * CAP * 8)     // float4[NPIX] = 8 MB

// Bin each patch into exactly ONE tile: the tile containing its top-left pixel.
__global__ __launch_bounds__(256) void bin_kernel(
    const int* __restrict__ nlInds, unsigned* __restrict__ cnt,
    uint2* __restrict__ ent, int N)
{
    int n = blockIdx.x * blockDim.x + threadIdx.x;
    if (n >= N) return;
    const int* ip = nlInds + (long)n * (KNN * 3);
    int ti = ip[0];
    int hi = ip[1] + PADV;   // in [3, 249]
    int wi = ip[2] + PADV;
    int tile = (ti * TPD + (hi >> 4)) * TPD + (wi >> 4);
    unsigned pos = atomicAdd(&cnt[tile], 1u);
    if (pos < CAP)   // statistically impossible to overflow; guard vs corruption
        ent[(long)tile * CAP + pos] = make_uint2((unsigned)n,
                                                 ((unsigned)hi << 8) | (unsigned)wi);
}

// One block per tile. Accumulate full patches into a 22x22 LDS region
// (own 16x16 + down-right halo of 6). x read fully coalesced (dwordx3/record).
__global__ __launch_bounds__(256) void agg_kernel(
    const float* __restrict__ x,
    const unsigned* __restrict__ cnt,
    const uint2* __restrict__ ent,
    float4* __restrict__ vid4)
{
    __shared__ float acc[4 * PLANE];
    int b   = blockIdx.x;
    int img = b >> 8;                 // / (TPD*TPD) = 256
    int rem = b & 255;
    int ty  = rem >> 4;
    int tx  = rem & 15;
    int tid = threadIdx.x;

    for (int i = tid; i < 4 * PLANE; i += 256) acc[i] = 0.f;
    __syncthreads();

    int lane = tid & 63;
    int wv   = tid >> 6;

    // per-lane loop-invariant decode of elements e = 3*lane .. 3*lane+2
    int c0, p0r, p0c, c1, p1r, p1c, c2, p2r, p2c;
    {
        int e = 3 * lane;
        c0 = e / PP; int rc = e % PP; p0r = rc / PS; p0c = rc % PS;
        e++; c1 = e / PP; rc = e % PP; p1r = rc / PS; p1c = rc % PS;
        e++; c2 = e / PP; rc = e % PP; p2r = rc / PS; p2c = rc % PS;
    }

    unsigned ne = cnt[b];
    if (ne > CAP) ne = CAP;
    const uint2* eb = ent + (long)b * CAP;

    for (unsigned e = wv; e < ne; e += 4) {
        uint2 en = eb[e];
        int hl = (int)((en.y >> 8) & 15u);   // local top-left row  [0,15]
        int wl = (int)(en.y & 15u);          // local top-left col  [0,15]
        if (lane < 49) {
            const float* xp = x + (long)en.x * FDIM + 3 * lane;
            float v0 = xp[0], v1 = xp[1], v2 = xp[2];
            int q0 = (hl + p0r) * EXT + (wl + p0c);
            int q1 = (hl + p1r) * EXT + (wl + p1c);
            int q2 = (hl + p2r) * EXT + (wl + p2c);
            atomicAdd(&acc[c0 * PLANE + q0], v0);
            atomicAdd(&acc[c1 * PLANE + q1], v1);
            atomicAdd(&acc[c2 * PLANE + q2], v2);
            // weight: +1 per patch position (channel-0 elements exactly cover 49 positions)
            if (c0 == 0) atomicAdd(&acc[3 * PLANE + q0], 1.f);
            if (c1 == 0) atomicAdd(&acc[3 * PLANE + q1], 1.f);
            if (c2 == 0) atomicAdd(&acc[3 * PLANE + q2], 1.f);
        }
    }
    __syncthreads();

    // write out: interior pixels (single-writer by construction) plain-store,
    // edge/halo pixels merge via global atomics into zeroed vid4.
    for (int p = tid; p < EXT * EXT; p += 256) {
        int r  = p / EXT, cc = p % EXT;
        int gr = ty * TS + r, gc = tx * TS + cc;
        if (gr >= HPIX || gc >= WPIX) continue;
        float vr = acc[p];
        float vg = acc[PLANE + p];
        float vb = acc[2 * PLANE + p];
        float vw = acc[3 * PLANE + p];
        if (vw == 0.f) continue;
        long idx = ((long)img * HPIX + gr) * WPIX + gc;
        bool interior = (r >= PS - 1) && (r < TS) && (cc >= PS - 1) && (cc < TS);
        if (interior) {
            vid4[idx] = make_float4(vr, vg, vb, vw);
        } else {
            float* vp = (float*)&vid4[idx];
            atomicAdd(vp + 0, vr);
            atomicAdd(vp + 1, vg);
            atomicAdd(vp + 2, vb);
            atomicAdd(vp + 3, vw);
        }
    }
}

// Gather with fused normalization (w rides in vid4.w).
__global__ __launch_bounds__(256) void gather_kernel(
    const float4* __restrict__ vid4,
    const int* __restrict__ nlInds,
    float* __restrict__ out, int N)
{
    long g = (long)blockIdx.x * blockDim.x + threadIdx.x;
    long total = (long)N * PP;
    if (g >= total) return;
    int n   = (int)(g / PP);
    int pos = (int)(g - (long)n * PP);
    int a    = pos / PS;
    int bcol = pos - a * PS;

    const int* ip = nlInds + (long)n * (KNN * 3);
    int ti = ip[0];
    int hi = ip[1] + PADV;
    int wi = ip[2] + PADV;
    int idx = ti * (HPIX * WPIX) + (hi + a) * WPIX + (wi + bcol);

    float4 v = vid4[idx];
    float w = (v.w > 0.f) ? v.w : 1.f;
    float* op = out + (long)n * FDIM + pos;
    op[0]      = v.x / w;
    op[PP]     = v.y / w;
    op[2 * PP] = v.z / w;
}

extern "C" void kernel_launch(void* const* d_in, const int* in_sizes, int n_in,
                              void* d_out, int out_size, void* d_ws, size_t ws_size,
                              hipStream_t stream)
{
    const float* x      = (const float*)d_in[0];
    const int*   nlInds = (const int*)d_in[2];
    float*       out    = (float*)d_out;

    char* ws = (char*)d_ws;
    unsigned* cnt  = (unsigned*)(ws + WS_CNT);
    uint2*    ent  = (uint2*)   (ws + WS_ENT);
    float4*   vid4 = (float4*)  (ws + WS_VID);

    int N = in_sizes[0] / FDIM;   // 524288

    hipMemsetAsync(cnt, 0, NTILE * sizeof(unsigned), stream);
    hipMemsetAsync(vid4, 0, (size_t)NPIX * sizeof(float4), stream);

    int blk = 256;
    int gN  = (N + blk - 1) / blk;

    bin_kernel<<<gN, blk, 0, stream>>>(nlInds, cnt, ent, N);
    agg_kernel<<<NTILE, blk, 0, stream>>>(x, cnt, ent, vid4);

    long total = (long)N * PP;
    int  gG    = (int)((total + blk - 1) / blk);
    gather_kernel<<<gG, blk, 0, stream>>>((const float4*)vid4, nlInds, out, N);
}

// Round 4
// 339.462 us; speedup vs baseline: 2.3407x; 2.3407x over previous
//
#include <hip/hip_runtime.h>

#define PS    7
#define PADV  3
#define PP    49      // PS*PS
#define FDIM  147     // 3*PP
#define KNN   5

// Fixed problem instance: t=8, p=65536, H=W=256
#define T_IMG 8
#define HPIX  256
#define WPIX  256
#define NPIX  (T_IMG * HPIX * WPIX)   // 524288

#define TS    16                      // tile size (own pixels)
#define TPD   16                      // tiles per dim
#define NTILE (T_IMG * TPD * TPD)     // 2048
#define CAP   512                     // entry slots/tile (mean ~275, sigma ~17)
#define EXT   22                      // TS + PS - 1
#define NPOS  (EXT * EXT)             // 484
#define WREGF (4 * NPOS)              // floats per wave-private region (4 planes)

// workspace layout (bytes); total ~23.2 MB (<= 26.1 MB validated in r2/r3)
#define WS_CNT  0                               // u32[NTILE]
#define WS_ENT  (64 * 1024)                     // uint2[NTILE*CAP] = 8 MB (reused as vid4 after agg)
#define WS_TILE (WS_ENT + NTILE * CAP * 8)      // float4[NTILE*NPOS] = 15.1 MB

// ---- bin: each patch into exactly one tile (containing its top-left) ----
__global__ __launch_bounds__(256) void bin_kernel(
    const int* __restrict__ nlInds, unsigned* __restrict__ cnt,
    uint2* __restrict__ ent, int N)
{
    int n = blockIdx.x * blockDim.x + threadIdx.x;
    if (n >= N) return;
    const int* ip = nlInds + (long)n * (KNN * 3);
    int ti = ip[0];
    int hi = ip[1] + PADV;   // [3, 249]
    int wi = ip[2] + PADV;
    int tile = (ti * TPD + (hi >> 4)) * TPD + (wi >> 4);
    unsigned pos = atomicAdd(&cnt[tile], 1u);   // integer atomic: native HW
    if (pos < CAP)
        ent[(long)tile * CAP + pos] = make_uint2((unsigned)n,
                                                 ((unsigned)hi << 8) | (unsigned)wi);
}

// ---- agg: one block per tile, wave-private LDS accumulators, NO atomics ----
__global__ __launch_bounds__(256) void agg_kernel(
    const float* __restrict__ x,
    const unsigned* __restrict__ cnt,
    const uint2* __restrict__ ent,
    float4* __restrict__ tilebuf)
{
    __shared__ float acc[4 * WREGF];   // 4 waves * 1936 floats = 30976 B
    int b   = blockIdx.x;
    int tid = threadIdx.x;

    for (int i = tid; i < 4 * WREGF; i += 256) acc[i] = 0.f;
    __syncthreads();

    int lane = tid & 63;
    int wv   = tid >> 6;
    float* A = acc + wv * WREGF;       // wave-private region

    // lane-constant decode: elements le, le+1, le+2 of the 147-float record
    int le = 3 * lane;
    int c0 = le / PP,        p0 = le % PP;
    int c1 = (le + 1) / PP,  p1 = (le + 1) % PP;
    int c2 = (le + 2) / PP,  p2 = (le + 2) % PP;
    int off0 = c0 * NPOS + (p0 / PS) * EXT + p0 % PS;
    int off1 = c1 * NPOS + (p1 / PS) * EXT + p1 % PS;
    int off2 = c2 * NPOS + (p2 / PS) * EXT + p2 % PS;
    int offw = 3 * NPOS + (lane / PS) * EXT + lane % PS;  // weight plane, lane<49
    bool act = lane < 49;

    unsigned ne = cnt[b];
    if (ne > CAP) ne = CAP;
    const uint2* eb = ent + (long)b * CAP;

    unsigned e = wv;
    for (; e + 4 < ne; e += 8) {
        uint2 EA = eb[e];
        uint2 EB = eb[e + 4];
        float a0 = 0.f, a1 = 0.f, a2 = 0.f, b0 = 0.f, b1 = 0.f, b2 = 0.f;
        const float* xa = x + (size_t)EA.x * FDIM + le;
        const float* xb = x + (size_t)EB.x * FDIM + le;
        if (act) {
            a0 = xa[0]; a1 = xa[1]; a2 = xa[2];
            b0 = xb[0]; b1 = xb[1]; b2 = xb[2];
        }
        int basA = (int)((EA.y >> 8) & 15u) * EXT + (int)(EA.y & 15u);
        int basB = (int)((EB.y >> 8) & 15u) * EXT + (int)(EB.y & 15u);
        if (act) {
            A[basA + off0] += a0;
            A[basA + off1] += a1;
            A[basA + off2] += a2;
            A[basA + offw] += 1.f;
            A[basB + off0] += b0;
            A[basB + off1] += b1;
            A[basB + off2] += b2;
            A[basB + offw] += 1.f;
        }
    }
    if (e < ne) {
        uint2 EA = eb[e];
        float a0 = 0.f, a1 = 0.f, a2 = 0.f;
        const float* xa = x + (size_t)EA.x * FDIM + le;
        if (act) { a0 = xa[0]; a1 = xa[1]; a2 = xa[2]; }
        int basA = (int)((EA.y >> 8) & 15u) * EXT + (int)(EA.y & 15u);
        if (act) {
            A[basA + off0] += a0;
            A[basA + off1] += a1;
            A[basA + off2] += a2;
            A[basA + offw] += 1.f;
        }
    }
    __syncthreads();

    // reduce the 4 wave regions, store full 22x22 tile (coalesced float4)
    long tb = (long)b * NPOS;
    for (int p = tid; p < NPOS; p += 256) {
        float vr = 0.f, vg = 0.f, vb = 0.f, vw = 0.f;
#pragma unroll
        for (int w = 0; w < 4; w++) {
            const float* R = acc + w * WREGF;
            vr += R[p];
            vg += R[NPOS + p];
            vb += R[2 * NPOS + p];
            vw += R[3 * NPOS + p];
        }
        tilebuf[tb + p] = make_float4(vr, vg, vb, vw);
    }
}

// ---- merge: deterministic halo combine + normalization, 1 thread/pixel ----
__global__ __launch_bounds__(256) void merge_kernel(
    const float4* __restrict__ tilebuf,
    float4* __restrict__ vid4)
{
    int i = blockIdx.x * blockDim.x + threadIdx.x;
    if (i >= NPIX) return;
    int img = i >> 16;
    int r   = (i >> 8) & 255;
    int c   = i & 255;
    int tr = r >> 4, lr = r & 15;
    int tc = c >> 4, lc = c & 15;
    int tbase = img * (TPD * TPD);

    float sx, sy, sz, sw;
    {
        float4 v = tilebuf[(long)(tbase + tr * TPD + tc) * NPOS + lr * EXT + lc];
        sx = v.x; sy = v.y; sz = v.z; sw = v.w;
    }
    if (lc < PS - 1 && tc > 0) {
        float4 v = tilebuf[(long)(tbase + tr * TPD + tc - 1) * NPOS + lr * EXT + (lc + TS)];
        sx += v.x; sy += v.y; sz += v.z; sw += v.w;
    }
    if (lr < PS - 1 && tr > 0) {
        float4 v = tilebuf[(long)(tbase + (tr - 1) * TPD + tc) * NPOS + (lr + TS) * EXT + lc];
        sx += v.x; sy += v.y; sz += v.z; sw += v.w;
    }
    if (lr < PS - 1 && lc < PS - 1 && tr > 0 && tc > 0) {
        float4 v = tilebuf[(long)(tbase + (tr - 1) * TPD + tc - 1) * NPOS + (lr + TS) * EXT + (lc + TS)];
        sx += v.x; sy += v.y; sz += v.z; sw += v.w;
    }
    float w = (sw > 0.f) ? sw : 1.f;
    vid4[i] = make_float4(sx / w, sy / w, sz / w, sw);
}

// ---- gather: values pre-normalized, plain copy-out ----
__global__ __launch_bounds__(256) void gather_kernel(
    const float4* __restrict__ vid4,
    const int* __restrict__ nlInds,
    float* __restrict__ out, int N)
{
    long g = (long)blockIdx.x * blockDim.x + threadIdx.x;
    long total = (long)N * PP;
    if (g >= total) return;
    int n   = (int)(g / PP);
    int pos = (int)(g - (long)n * PP);
    int a    = pos / PS;
    int bcol = pos - a * PS;

    const int* ip = nlInds + (long)n * (KNN * 3);
    int ti = ip[0];
    int hi = ip[1] + PADV;
    int wi = ip[2] + PADV;
    int idx = ti * (HPIX * WPIX) + (hi + a) * WPIX + (wi + bcol);

    float4 v = vid4[idx];
    float* op = out + (long)n * FDIM + pos;
    op[0]      = v.x;
    op[PP]     = v.y;
    op[2 * PP] = v.z;
}

extern "C" void kernel_launch(void* const* d_in, const int* in_sizes, int n_in,
                              void* d_out, int out_size, void* d_ws, size_t ws_size,
                              hipStream_t stream)
{
    const float* x      = (const float*)d_in[0];
    const int*   nlInds = (const int*)d_in[2];
    float*       out    = (float*)d_out;

    char* ws = (char*)d_ws;
    unsigned* cnt     = (unsigned*)(ws + WS_CNT);
    uint2*    ent     = (uint2*)   (ws + WS_ENT);
    float4*   tilebuf = (float4*)  (ws + WS_TILE);
    float4*   vid4    = (float4*)  (ws + WS_ENT);   // reuse ent space after agg

    int N = in_sizes[0] / FDIM;   // 524288

    hipMemsetAsync(cnt, 0, NTILE * sizeof(unsigned), stream);

    int blk = 256;
    int gN  = (N + blk - 1) / blk;

    bin_kernel<<<gN, blk, 0, stream>>>(nlInds, cnt, ent, N);
    agg_kernel<<<NTILE, blk, 0, stream>>>(x, cnt, ent, tilebuf);
    merge_kernel<<<(NPIX + blk - 1) / blk, blk, 0, stream>>>(tilebuf, vid4);

    long total = (long)N * PP;
    int  gG    = (int)((total + blk - 1) / blk);
    gather_kernel<<<gG, blk, 0, stream>>>((const float4*)vid4, nlInds, out, N);
}

// Round 5
// 329.180 us; speedup vs baseline: 2.4139x; 1.0312x over previous
//
#include <hip/hip_runtime.h>

#define PS    7
#define PADV  3
#define PP    49      // PS*PS
#define FDIM  147     // 3*PP
#define KNN   5

// Fixed problem instance: t=8, p=65536, H=W=256
#define T_IMG 8
#define HPIX  256
#define WPIX  256
#define NPIX  (T_IMG * HPIX * WPIX)   // 524288

#define TS    16                      // tile size (own pixels)
#define TPD   16                      // tiles per dim
#define NTILE (T_IMG * TPD * TPD)     // 2048
#define CAP   512                     // entry slots/tile (mean ~275, sigma ~17)
#define EXT   22                      // TS + PS - 1
#define NPOS  (EXT * EXT)             // 484
#define WREGF (4 * NPOS)              // floats per wave-private region (4 planes)

// workspace layout (bytes); total ~23.2 MB
#define WS_CNT  0                               // u32[NTILE]
#define WS_ENT  (64 * 1024)                     // uint2[NTILE*CAP] = 8 MB (reused as vid4 after agg)
#define WS_TILE (WS_ENT + NTILE * CAP * 8)      // float4[NTILE*NPOS] = 15.1 MB

// ---- bin: each patch into exactly one tile (containing its top-left) ----
__global__ __launch_bounds__(256) void bin_kernel(
    const int* __restrict__ nlInds, unsigned* __restrict__ cnt,
    uint2* __restrict__ ent, int N)
{
    int n = blockIdx.x * blockDim.x + threadIdx.x;
    if (n >= N) return;
    const int* ip = nlInds + (long)n * (KNN * 3);
    int ti = ip[0];
    int hi = ip[1] + PADV;   // [3, 249]
    int wi = ip[2] + PADV;
    int tile = (ti * TPD + (hi >> 4)) * TPD + (wi >> 4);
    unsigned pos = atomicAdd(&cnt[tile], 1u);   // integer atomic: native HW
    if (pos < CAP)
        ent[(long)tile * CAP + pos] = make_uint2((unsigned)n,
                                                 ((unsigned)hi << 8) | (unsigned)wi);
}

// ---- agg: one block per tile, wave-private LDS accumulators, NO atomics ----
__global__ __launch_bounds__(256) void agg_kernel(
    const float* __restrict__ x,
    const unsigned* __restrict__ cnt,
    const uint2* __restrict__ ent,
    float4* __restrict__ tilebuf)
{
    __shared__ float acc[4 * WREGF];   // 4 waves * 1936 floats = 30976 B
    int b   = blockIdx.x;
    int tid = threadIdx.x;

    for (int i = tid; i < 4 * WREGF; i += 256) acc[i] = 0.f;
    __syncthreads();

    int lane = tid & 63;
    int wv   = tid >> 6;
    float* A = acc + wv * WREGF;       // wave-private region

    // lane-constant decode: elements le, le+1, le+2 of the 147-float record
    int le = 3 * lane;
    int c0 = le / PP,        p0 = le % PP;
    int c1 = (le + 1) / PP,  p1 = (le + 1) % PP;
    int c2 = (le + 2) / PP,  p2 = (le + 2) % PP;
    int off0 = c0 * NPOS + (p0 / PS) * EXT + p0 % PS;
    int off1 = c1 * NPOS + (p1 / PS) * EXT + p1 % PS;
    int off2 = c2 * NPOS + (p2 / PS) * EXT + p2 % PS;
    int offw = 3 * NPOS + (lane / PS) * EXT + lane % PS;  // weight plane, lane<49
    bool act = lane < 49;

    unsigned ne = cnt[b];
    if (ne > CAP) ne = CAP;
    const uint2* eb = ent + (long)b * CAP;

    unsigned e = wv;
    for (; e + 4 < ne; e += 8) {
        uint2 EA = eb[e];
        uint2 EB = eb[e + 4];
        float a0 = 0.f, a1 = 0.f, a2 = 0.f, b0 = 0.f, b1 = 0.f, b2 = 0.f;
        const float* xa = x + (size_t)EA.x * FDIM + le;
        const float* xb = x + (size_t)EB.x * FDIM + le;
        if (act) {
            a0 = xa[0]; a1 = xa[1]; a2 = xa[2];
            b0 = xb[0]; b1 = xb[1]; b2 = xb[2];
        }
        int basA = (int)((EA.y >> 8) & 15u) * EXT + (int)(EA.y & 15u);
        int basB = (int)((EB.y >> 8) & 15u) * EXT + (int)(EB.y & 15u);
        if (act) {
            A[basA + off0] += a0;
            A[basA + off1] += a1;
            A[basA + off2] += a2;
            A[basA + offw] += 1.f;
            A[basB + off0] += b0;
            A[basB + off1] += b1;
            A[basB + off2] += b2;
            A[basB + offw] += 1.f;
        }
    }
    if (e < ne) {
        uint2 EA = eb[e];
        float a0 = 0.f, a1 = 0.f, a2 = 0.f;
        const float* xa = x + (size_t)EA.x * FDIM + le;
        if (act) { a0 = xa[0]; a1 = xa[1]; a2 = xa[2]; }
        int basA = (int)((EA.y >> 8) & 15u) * EXT + (int)(EA.y & 15u);
        if (act) {
            A[basA + off0] += a0;
            A[basA + off1] += a1;
            A[basA + off2] += a2;
            A[basA + offw] += 1.f;
        }
    }
    __syncthreads();

    // reduce the 4 wave regions, store full 22x22 tile (coalesced float4)
    long tb = (long)b * NPOS;
    for (int p = tid; p < NPOS; p += 256) {
        float vr = 0.f, vg = 0.f, vb = 0.f, vw = 0.f;
#pragma unroll
        for (int w = 0; w < 4; w++) {
            const float* R = acc + w * WREGF;
            vr += R[p];
            vg += R[NPOS + p];
            vb += R[2 * NPOS + p];
            vw += R[3 * NPOS + p];
        }
        tilebuf[tb + p] = make_float4(vr, vg, vb, vw);
    }
}

// ---- merge: deterministic halo combine + normalization, 1 thread/pixel ----
__global__ __launch_bounds__(256) void merge_kernel(
    const float4* __restrict__ tilebuf,
    float4* __restrict__ vid4)
{
    int i = blockIdx.x * blockDim.x + threadIdx.x;
    if (i >= NPIX) return;
    int img = i >> 16;
    int r   = (i >> 8) & 255;
    int c   = i & 255;
    int tr = r >> 4, lr = r & 15;
    int tc = c >> 4, lc = c & 15;
    int tbase = img * (TPD * TPD);

    float sx, sy, sz, sw;
    {
        float4 v = tilebuf[(long)(tbase + tr * TPD + tc) * NPOS + lr * EXT + lc];
        sx = v.x; sy = v.y; sz = v.z; sw = v.w;
    }
    if (lc < PS - 1 && tc > 0) {
        float4 v = tilebuf[(long)(tbase + tr * TPD + tc - 1) * NPOS + lr * EXT + (lc + TS)];
        sx += v.x; sy += v.y; sz += v.z; sw += v.w;
    }
    if (lr < PS - 1 && tr > 0) {
        float4 v = tilebuf[(long)(tbase + (tr - 1) * TPD + tc) * NPOS + (lr + TS) * EXT + lc];
        sx += v.x; sy += v.y; sz += v.z; sw += v.w;
    }
    if (lr < PS - 1 && lc < PS - 1 && tr > 0 && tc > 0) {
        float4 v = tilebuf[(long)(tbase + (tr - 1) * TPD + tc - 1) * NPOS + (lr + TS) * EXT + (lc + TS)];
        sx += v.x; sy += v.y; sz += v.z; sw += v.w;
    }
    float w = (sw > 0.f) ? sw : 1.f;
    vid4[i] = make_float4(sx / w, sy / w, sz / w, sw);
}

// ---- gather: block-staged. 16 patches/block; idx computed once/patch;
//      wave-per-patch float4 loads; coalesced float4 stores via LDS. ----
__global__ __launch_bounds__(256) void gather_kernel(
    const float4* __restrict__ vid4,
    const int* __restrict__ nlInds,
    float* __restrict__ out)
{
    __shared__ __align__(16) float so[16 * FDIM];   // 2352 floats = 9408 B
    __shared__ int idxb[16];

    int tid = threadIdx.x;
    int n0  = blockIdx.x * 16;

    if (tid < 16) {
        const int* ip = nlInds + (size_t)(n0 + tid) * (KNN * 3);
        idxb[tid] = ip[0] * (HPIX * WPIX) + (ip[1] + PADV) * WPIX + (ip[2] + PADV);
    }
    __syncthreads();

    int lane = tid & 63;
    int wv   = tid >> 6;
    int voff = (lane / PS) * WPIX + (lane % PS);    // lane-const window offset

    if (lane < PP) {
#pragma unroll
        for (int it = 0; it < 4; ++it) {
            int p = wv * 4 + it;
            float4 v = vid4[idxb[p] + voff];
            float* sp = so + p * FDIM + lane;
            sp[0]      = v.x;
            sp[PP]     = v.y;
            sp[2 * PP] = v.z;
        }
    }
    __syncthreads();

    float4*       outv = (float4*)(out + (size_t)n0 * FDIM);
    const float4* sov  = (const float4*)so;
#pragma unroll
    for (int i = 0; i < 2; ++i) {
        int j = tid + i * 256;
        outv[j] = sov[j];
    }
    {   // 588 = 2*256 + 76
        int j = tid + 512;
        if (j < (16 * FDIM) / 4) outv[j] = sov[j];
    }
}

extern "C" void kernel_launch(void* const* d_in, const int* in_sizes, int n_in,
                              void* d_out, int out_size, void* d_ws, size_t ws_size,
                              hipStream_t stream)
{
    const float* x      = (const float*)d_in[0];
    const int*   nlInds = (const int*)d_in[2];
    float*       out    = (float*)d_out;

    char* ws = (char*)d_ws;
    unsigned* cnt     = (unsigned*)(ws + WS_CNT);
    uint2*    ent     = (uint2*)   (ws + WS_ENT);
    float4*   tilebuf = (float4*)  (ws + WS_TILE);
    float4*   vid4    = (float4*)  (ws + WS_ENT);   // reuse ent space after agg

    int N = in_sizes[0] / FDIM;   // 524288

    hipMemsetAsync(cnt, 0, NTILE * sizeof(unsigned), stream);

    int blk = 256;
    int gN  = (N + blk - 1) / blk;

    bin_kernel<<<gN, blk, 0, stream>>>(nlInds, cnt, ent, N);
    agg_kernel<<<NTILE, blk, 0, stream>>>(x, cnt, ent, tilebuf);
    merge_kernel<<<(NPIX + blk - 1) / blk, blk, 0, stream>>>(tilebuf, vid4);
    gather_kernel<<<N / 16, blk, 0, stream>>>((const float4*)vid4, nlInds, out);
}

// Round 6
// 295.816 us; speedup vs baseline: 2.6861x; 1.1128x over previous
//
#include <hip/hip_runtime.h>

#define PS    7
#define PADV  3
#define PP    49      // PS*PS
#define FDIM  147     // 3*PP
#define KNN   5

// Fixed problem instance: t=8, p=65536, H=W=256
#define T_IMG 8
#define HPIX  256
#define WPIX  256
#define NPIX  (T_IMG * HPIX * WPIX)   // 524288

#define TS    16                      // tile size (own pixels)
#define TPD   16                      // tiles per dim
#define NTILE (T_IMG * TPD * TPD)     // 2048
#define CAP   512                     // entry slots/tile (mean ~275, sigma ~17)
#define EXT   22                      // TS + PS - 1
#define NPOS  (EXT * EXT)             // 484

// workspace layout (bytes); total ~32.7 MB (harness ws ~1.2 GB per poison fill)
#define WS_CNT  0                                   // u32[NTILE]
#define WS_ENT  (64 * 1024)                         // uint2[NTILE*CAP] = 8 MB
#define WS_TILE (WS_ENT + NTILE * CAP * 8)          // float4[NTILE*NPOS] = 15.1 MB
#define WS_VID  (WS_TILE + NTILE * NPOS * 16)       // float4[NPIX] = 8 MB

// ---- bin: each patch into exactly one tile (containing its top-left) ----
__global__ __launch_bounds__(256) void bin_kernel(
    const int* __restrict__ nlInds, unsigned* __restrict__ cnt,
    uint2* __restrict__ ent, int N)
{
    int n = blockIdx.x * blockDim.x + threadIdx.x;
    if (n >= N) return;
    const int* ip = nlInds + (long)n * (KNN * 3);
    int ti = ip[0];
    int hi = ip[1] + PADV;   // [3, 249]
    int wi = ip[2] + PADV;
    int tile = (ti * TPD + (hi >> 4)) * TPD + (wi >> 4);
    unsigned pos = atomicAdd(&cnt[tile], 1u);   // integer atomic: native HW
    if (pos < CAP)
        ent[(long)tile * CAP + pos] = make_uint2((unsigned)n,
                                                 ((unsigned)hi << 8) | (unsigned)wi);
}

// ---- agg: one block per tile, wave-private LDS float4 accumulators ----
// lane l < 49 owns patch position l: loads x[l], x[49+l], x[98+l]
// (3 coalesced 196B wave-loads) and does ONE float4 LDS RMW per entry.
__global__ __launch_bounds__(256) void agg_kernel(
    const float* __restrict__ x,
    const unsigned* __restrict__ cnt,
    const uint2* __restrict__ ent,
    float4* __restrict__ tilebuf)
{
    __shared__ float4 acc[4 * NPOS];   // 4 waves * 484 * 16B = 30976 B
    int b   = blockIdx.x;
    int tid = threadIdx.x;

    for (int i = tid; i < 4 * NPOS; i += 256)
        acc[i] = make_float4(0.f, 0.f, 0.f, 0.f);
    __syncthreads();

    int lane = tid & 63;
    int wv   = tid >> 6;
    float4* A = acc + wv * NPOS;       // wave-private region

    int poff = (lane / PS) * EXT + (lane % PS);   // lane's position offset in EXT grid
    bool act = lane < PP;

    unsigned ne = cnt[b];
    if (ne > CAP) ne = CAP;
    const uint2* eb = ent + (long)b * CAP;

    unsigned e = wv;
    for (; e + 4 < ne; e += 8) {
        uint2 EA = eb[e];
        uint2 EB = eb[e + 4];
        float a0 = 0.f, a1 = 0.f, a2 = 0.f, b0 = 0.f, b1 = 0.f, b2 = 0.f;
        const float* xa = x + (size_t)EA.x * FDIM + lane;
        const float* xb = x + (size_t)EB.x * FDIM + lane;
        if (act) {
            a0 = xa[0]; a1 = xa[PP]; a2 = xa[2 * PP];
            b0 = xb[0]; b1 = xb[PP]; b2 = xb[2 * PP];
        }
        int qa = (int)((EA.y >> 8) & 15u) * EXT + (int)(EA.y & 15u) + poff;
        int qb = (int)((EB.y >> 8) & 15u) * EXT + (int)(EB.y & 15u) + poff;
        if (act) {
            float4 v = A[qa];
            v.x += a0; v.y += a1; v.z += a2; v.w += 1.f;
            A[qa] = v;
            float4 u = A[qb];
            u.x += b0; u.y += b1; u.z += b2; u.w += 1.f;
            A[qb] = u;
        }
    }
    if (e < ne) {
        uint2 EA = eb[e];
        float a0 = 0.f, a1 = 0.f, a2 = 0.f;
        const float* xa = x + (size_t)EA.x * FDIM + lane;
        if (act) { a0 = xa[0]; a1 = xa[PP]; a2 = xa[2 * PP]; }
        int qa = (int)((EA.y >> 8) & 15u) * EXT + (int)(EA.y & 15u) + poff;
        if (act) {
            float4 v = A[qa];
            v.x += a0; v.y += a1; v.z += a2; v.w += 1.f;
            A[qa] = v;
        }
    }
    __syncthreads();

    // reduce the 4 wave regions, store full 22x22 tile (coalesced float4)
    long tb = (long)b * NPOS;
    for (int p = tid; p < NPOS; p += 256) {
        float4 s = acc[p];
        float4 v1 = acc[NPOS + p];
        float4 v2 = acc[2 * NPOS + p];
        float4 v3 = acc[3 * NPOS + p];
        s.x += v1.x + v2.x + v3.x;
        s.y += v1.y + v2.y + v3.y;
        s.z += v1.z + v2.z + v3.z;
        s.w += v1.w + v2.w + v3.w;
        tilebuf[tb + p] = s;
    }
}

// ---- merge: deterministic halo combine + normalization, 1 thread/pixel ----
__global__ __launch_bounds__(256) void merge_kernel(
    const float4* __restrict__ tilebuf,
    float4* __restrict__ vid4)
{
    int i = blockIdx.x * blockDim.x + threadIdx.x;
    if (i >= NPIX) return;
    int img = i >> 16;
    int r   = (i >> 8) & 255;
    int c   = i & 255;
    int tr = r >> 4, lr = r & 15;
    int tc = c >> 4, lc = c & 15;
    int tbase = img * (TPD * TPD);

    float sx, sy, sz, sw;
    {
        float4 v = tilebuf[(long)(tbase + tr * TPD + tc) * NPOS + lr * EXT + lc];
        sx = v.x; sy = v.y; sz = v.z; sw = v.w;
    }
    if (lc < PS - 1 && tc > 0) {
        float4 v = tilebuf[(long)(tbase + tr * TPD + tc - 1) * NPOS + lr * EXT + (lc + TS)];
        sx += v.x; sy += v.y; sz += v.z; sw += v.w;
    }
    if (lr < PS - 1 && tr > 0) {
        float4 v = tilebuf[(long)(tbase + (tr - 1) * TPD + tc) * NPOS + (lr + TS) * EXT + lc];
        sx += v.x; sy += v.y; sz += v.z; sw += v.w;
    }
    if (lr < PS - 1 && lc < PS - 1 && tr > 0 && tc > 0) {
        float4 v = tilebuf[(long)(tbase + (tr - 1) * TPD + tc - 1) * NPOS + (lr + TS) * EXT + (lc + TS)];
        sx += v.x; sy += v.y; sz += v.z; sw += v.w;
    }
    float w = (sw > 0.f) ? sw : 1.f;
    vid4[i] = make_float4(sx / w, sy / w, sz / w, sw);
}

// ---- gather: one block per tile. Stage the tile's 22x22 normalized window
//      in LDS once; per entry, 49 lanes read LDS and store 3x196B runs. ----
__global__ __launch_bounds__(256) void gather_kernel(
    const float4* __restrict__ vid4,
    const unsigned* __restrict__ cnt,
    const uint2* __restrict__ ent,
    float* __restrict__ out)
{
    __shared__ float4 win[NPOS];   // 7744 B
    int b   = blockIdx.x;
    int img = b >> 8;
    int rem = b & 255;
    int ty  = rem >> 4;
    int tx  = rem & 15;
    int tid = threadIdx.x;

    int ibase = img * (HPIX * WPIX);
    for (int p = tid; p < NPOS; p += 256) {
        int r = p / EXT, c = p % EXT;
        int gr = ty * TS + r, gc = tx * TS + c;
        float4 v = make_float4(0.f, 0.f, 0.f, 0.f);
        if (gr < HPIX && gc < WPIX) v = vid4[ibase + gr * WPIX + gc];
        win[p] = v;
    }
    __syncthreads();

    int lane = tid & 63;
    int wv   = tid >> 6;
    int poff = (lane / PS) * EXT + (lane % PS);
    bool act = lane < PP;

    unsigned ne = cnt[b];
    if (ne > CAP) ne = CAP;
    const uint2* eb = ent + (long)b * CAP;

    for (unsigned e = wv; e < ne; e += 4) {
        uint2 E = eb[e];
        int q = (int)((E.y >> 8) & 15u) * EXT + (int)(E.y & 15u) + poff;
        if (act) {
            float4 v = win[q];
            float* op = out + (size_t)E.x * FDIM + lane;
            op[0]      = v.x;
            op[PP]     = v.y;
            op[2 * PP] = v.z;
        }
    }
}

extern "C" void kernel_launch(void* const* d_in, const int* in_sizes, int n_in,
                              void* d_out, int out_size, void* d_ws, size_t ws_size,
                              hipStream_t stream)
{
    const float* x      = (const float*)d_in[0];
    const int*   nlInds = (const int*)d_in[2];
    float*       out    = (float*)d_out;

    char* ws = (char*)d_ws;
    unsigned* cnt     = (unsigned*)(ws + WS_CNT);
    uint2*    ent     = (uint2*)   (ws + WS_ENT);
    float4*   tilebuf = (float4*)  (ws + WS_TILE);
    float4*   vid4    = (float4*)  (ws + WS_VID);

    int N = in_sizes[0] / FDIM;   // 524288

    hipMemsetAsync(cnt, 0, NTILE * sizeof(unsigned), stream);

    int blk = 256;
    int gN  = (N + blk - 1) / blk;

    bin_kernel<<<gN, blk, 0, stream>>>(nlInds, cnt, ent, N);
    agg_kernel<<<NTILE, blk, 0, stream>>>(x, cnt, ent, tilebuf);
    merge_kernel<<<(NPIX + blk - 1) / blk, blk, 0, stream>>>(tilebuf, vid4);
    gather_kernel<<<NTILE, blk, 0, stream>>>((const float4*)vid4, cnt, ent, out);
}

// Round 7
// 280.097 us; speedup vs baseline: 2.8369x; 1.0561x over previous
//
#include <hip/hip_runtime.h>

#define PS    7
#define PADV  3
#define PP    49      // PS*PS
#define FDIM  147     // 3*PP
#define KNN   5

// Fixed problem instance: t=8, p=65536, H=W=256
#define T_IMG 8
#define HPIX  256
#define WPIX  256
#define NPIX  (T_IMG * HPIX * WPIX)   // 524288

#define TS    16                      // tile size (own pixels)
#define TPD   16                      // tiles per dim
#define NTILE (T_IMG * TPD * TPD)     // 2048
#define CAP   512                     // entry slots/tile (mean 256, sigma ~16)
#define EXT   22                      // TS + PS - 1
#define NPOS  (EXT * EXT)             // 484

// workspace layout (bytes); total ~23.2 MB
#define WS_CNT  0                                   // u32[NTILE]
#define WS_ENT  (64 * 1024)                         // uint2[NTILE*CAP] = 8 MB
#define WS_TILE (WS_ENT + NTILE * CAP * 8)          // float4[NTILE*NPOS] = 15.1 MB

// ---- bin: each patch into exactly one tile (containing its top-left) ----
__global__ __launch_bounds__(256) void bin_kernel(
    const int* __restrict__ nlInds, unsigned* __restrict__ cnt,
    uint2* __restrict__ ent, int N)
{
    int n = blockIdx.x * blockDim.x + threadIdx.x;
    if (n >= N) return;
    const int* ip = nlInds + (long)n * (KNN * 3);
    int ti = ip[0];
    int hi = ip[1] + PADV;   // [3, 249]
    int wi = ip[2] + PADV;
    int tile = (ti * TPD + (hi >> 4)) * TPD + (wi >> 4);
    unsigned pos = atomicAdd(&cnt[tile], 1u);   // integer atomic: native HW
    if (pos < CAP)
        ent[(long)tile * CAP + pos] = make_uint2((unsigned)n,
                                                 ((unsigned)hi << 8) | (unsigned)wi);
}

// ---- agg: one block per tile, wave-private LDS float4 accumulators,
//      4-deep entry unroll to keep 12+ VMEM loads in flight ----
__global__ __launch_bounds__(256) void agg_kernel(
    const float* __restrict__ x,
    const unsigned* __restrict__ cnt,
    const uint2* __restrict__ ent,
    float4* __restrict__ tilebuf)
{
    __shared__ float4 acc[4 * NPOS];   // 4 waves * 484 * 16B = 30976 B
    int b   = blockIdx.x;
    int tid = threadIdx.x;

    for (int i = tid; i < 4 * NPOS; i += 256)
        acc[i] = make_float4(0.f, 0.f, 0.f, 0.f);
    __syncthreads();

    int lane = tid & 63;
    int wv   = tid >> 6;
    float4* A = acc + wv * NPOS;       // wave-private region

    int poff = (lane / PS) * EXT + (lane % PS);   // lane's position in EXT grid
    bool act = lane < PP;

    unsigned ne = cnt[b];
    if (ne > CAP) ne = CAP;
    const uint2* eb = ent + (long)b * CAP;

    unsigned e = wv;
    for (; e + 12 < ne; e += 16) {
        uint2 E0 = eb[e];
        uint2 E1 = eb[e + 4];
        uint2 E2 = eb[e + 8];
        uint2 E3 = eb[e + 12];
        float a0 = 0.f, a1 = 0.f, a2 = 0.f;
        float b0 = 0.f, b1 = 0.f, b2 = 0.f;
        float c0 = 0.f, c1 = 0.f, c2 = 0.f;
        float d0 = 0.f, d1 = 0.f, d2 = 0.f;
        if (act) {
            const float* x0 = x + (size_t)E0.x * FDIM + lane;
            const float* x1 = x + (size_t)E1.x * FDIM + lane;
            const float* x2 = x + (size_t)E2.x * FDIM + lane;
            const float* x3 = x + (size_t)E3.x * FDIM + lane;
            a0 = x0[0]; a1 = x0[PP]; a2 = x0[2 * PP];
            b0 = x1[0]; b1 = x1[PP]; b2 = x1[2 * PP];
            c0 = x2[0]; c1 = x2[PP]; c2 = x2[2 * PP];
            d0 = x3[0]; d1 = x3[PP]; d2 = x3[2 * PP];
        }
        int q0 = (int)((E0.y >> 8) & 15u) * EXT + (int)(E0.y & 15u) + poff;
        int q1 = (int)((E1.y >> 8) & 15u) * EXT + (int)(E1.y & 15u) + poff;
        int q2 = (int)((E2.y >> 8) & 15u) * EXT + (int)(E2.y & 15u) + poff;
        int q3 = (int)((E3.y >> 8) & 15u) * EXT + (int)(E3.y & 15u) + poff;
        if (act) {
            float4 v0 = A[q0];
            v0.x += a0; v0.y += a1; v0.z += a2; v0.w += 1.f;
            A[q0] = v0;
            float4 v1 = A[q1];
            v1.x += b0; v1.y += b1; v1.z += b2; v1.w += 1.f;
            A[q1] = v1;
            float4 v2 = A[q2];
            v2.x += c0; v2.y += c1; v2.z += c2; v2.w += 1.f;
            A[q2] = v2;
            float4 v3 = A[q3];
            v3.x += d0; v3.y += d1; v3.z += d2; v3.w += 1.f;
            A[q3] = v3;
        }
    }
    for (; e < ne; e += 4) {
        uint2 E0 = eb[e];
        float a0 = 0.f, a1 = 0.f, a2 = 0.f;
        if (act) {
            const float* x0 = x + (size_t)E0.x * FDIM + lane;
            a0 = x0[0]; a1 = x0[PP]; a2 = x0[2 * PP];
        }
        int q0 = (int)((E0.y >> 8) & 15u) * EXT + (int)(E0.y & 15u) + poff;
        if (act) {
            float4 v0 = A[q0];
            v0.x += a0; v0.y += a1; v0.z += a2; v0.w += 1.f;
            A[q0] = v0;
        }
    }
    __syncthreads();

    // reduce the 4 wave regions, store full 22x22 tile (coalesced float4)
    long tb = (long)b * NPOS;
    for (int p = tid; p < NPOS; p += 256) {
        float4 s  = acc[p];
        float4 v1 = acc[NPOS + p];
        float4 v2 = acc[2 * NPOS + p];
        float4 v3 = acc[3 * NPOS + p];
        s.x += v1.x + v2.x + v3.x;
        s.y += v1.y + v2.y + v3.y;
        s.z += v1.z + v2.z + v3.z;
        s.w += v1.w + v2.w + v3.w;
        tilebuf[tb + p] = s;
    }
}

// ---- gather: one block per tile. Stage the tile's 22x22 window with the
//      halo-merge + normalization fused (reads tilebuf directly, <=4 tiles
//      per pixel); then per entry, 49 lanes read LDS, store 3x196B runs. ----
__global__ __launch_bounds__(256) void gather_kernel(
    const float4* __restrict__ tilebuf,
    const unsigned* __restrict__ cnt,
    const uint2* __restrict__ ent,
    float* __restrict__ out)
{
    __shared__ float4 win[NPOS];   // 7744 B
    int b   = blockIdx.x;
    int img = b >> 8;
    int rem = b & 255;
    int ty  = rem >> 4;
    int tx  = rem & 15;
    int tid = threadIdx.x;
    int tbase = img * (TPD * TPD);

    for (int p = tid; p < NPOS; p += 256) {
        int r = p / EXT, c = p % EXT;
        int gr = ty * TS + r, gc = tx * TS + c;
        float sx = 0.f, sy = 0.f, sz = 0.f, sw = 0.f;
        if (gr < HPIX && gc < WPIX) {
            int tr = gr >> 4, lr = gr & 15;
            int tc = gc >> 4, lc = gc & 15;
            {
                float4 v = tilebuf[(long)(tbase + tr * TPD + tc) * NPOS + lr * EXT + lc];
                sx = v.x; sy = v.y; sz = v.z; sw = v.w;
            }
            if (lc < PS - 1 && tc > 0) {
                float4 v = tilebuf[(long)(tbase + tr * TPD + tc - 1) * NPOS + lr * EXT + (lc + TS)];
                sx += v.x; sy += v.y; sz += v.z; sw += v.w;
            }
            if (lr < PS - 1 && tr > 0) {
                float4 v = tilebuf[(long)(tbase + (tr - 1) * TPD + tc) * NPOS + (lr + TS) * EXT + lc];
                sx += v.x; sy += v.y; sz += v.z; sw += v.w;
            }
            if (lr < PS - 1 && lc < PS - 1 && tr > 0 && tc > 0) {
                float4 v = tilebuf[(long)(tbase + (tr - 1) * TPD + tc - 1) * NPOS + (lr + TS) * EXT + (lc + TS)];
                sx += v.x; sy += v.y; sz += v.z; sw += v.w;
            }
            float w = (sw > 0.f) ? sw : 1.f;
            sx /= w; sy /= w; sz /= w;
        }
        win[p] = make_float4(sx, sy, sz, sw);
    }
    __syncthreads();

    int lane = tid & 63;
    int wv   = tid >> 6;
    int poff = (lane / PS) * EXT + (lane % PS);
    bool act = lane < PP;

    unsigned ne = cnt[b];
    if (ne > CAP) ne = CAP;
    const uint2* eb = ent + (long)b * CAP;

    for (unsigned e = wv; e < ne; e += 4) {
        uint2 E = eb[e];
        int q = (int)((E.y >> 8) & 15u) * EXT + (int)(E.y & 15u) + poff;
        if (act) {
            float4 v = win[q];
            float* op = out + (size_t)E.x * FDIM + lane;
            op[0]      = v.x;
            op[PP]     = v.y;
            op[2 * PP] = v.z;
        }
    }
}

extern "C" void kernel_launch(void* const* d_in, const int* in_sizes, int n_in,
                              void* d_out, int out_size, void* d_ws, size_t ws_size,
                              hipStream_t stream)
{
    const float* x      = (const float*)d_in[0];
    const int*   nlInds = (const int*)d_in[2];
    float*       out    = (float*)d_out;

    char* ws = (char*)d_ws;
    unsigned* cnt     = (unsigned*)(ws + WS_CNT);
    uint2*    ent     = (uint2*)   (ws + WS_ENT);
    float4*   tilebuf = (float4*)  (ws + WS_TILE);

    int N = in_sizes[0] / FDIM;   // 524288

    hipMemsetAsync(cnt, 0, NTILE * sizeof(unsigned), stream);

    int blk = 256;
    int gN  = (N + blk - 1) / blk;

    bin_kernel<<<gN, blk, 0, stream>>>(nlInds, cnt, ent, N);
    agg_kernel<<<NTILE, blk, 0, stream>>>(x, cnt, ent, tilebuf);
    gather_kernel<<<NTILE, blk, 0, stream>>>((const float4*)tilebuf, cnt, ent, out);
}